// Round 7
// baseline (9519.855 us; speedup 1.0000x reference)
//
#include <hip/hip_runtime.h>
#include <math.h>

#define BB 8      // batch
#define KCH 10    // Chebyshev order
#define NB 64     // blocks for hist/scatter
#define TILE 8192 // LDS histogram tile (32 KB)
#define GRD(n) ((int)(((n) + 255) / 256))

__device__ __forceinline__ float elu_f(float x){ return x > 0.f ? x : expf(x) - 1.f; }

// x input is [B, V] fp32 -> x0 [V, B] fp32
__global__ void transpose_in(const float* __restrict__ x, float* __restrict__ x0, int V){
  int i = blockIdx.x*256 + threadIdx.x;
  if (i < BB*V){
    int b = i / V, v = i - b*V;
    x0[(long)v*BB + b] = x[i];
  }
}

// ---------------- CSR build (LDS atomics only; proven exact in R6) ----------------

__global__ void hist2d(const int* __restrict__ rows, int* __restrict__ bh, int E, int V){
  __shared__ int lh[TILE];
  int b = blockIdx.x;
  int per = (E + NB - 1) / NB;
  int e0 = b*per, e1 = (e0 + per < E) ? e0 + per : E;
  for (int t0 = 0; t0 < V; t0 += TILE){
    int tl = (V - t0 < TILE) ? (V - t0) : TILE;
    for (int i = threadIdx.x; i < tl; i += 256) lh[i] = 0;
    __syncthreads();
    for (int e = e0 + (int)threadIdx.x; e < e1; e += 256){
      int r = rows[e] - t0;
      if (r >= 0 && r < tl) atomicAdd(&lh[r], 1);
    }
    __syncthreads();
    for (int i = threadIdx.x; i < tl; i += 256) bh[(long)b*V + t0 + i] = lh[i];
    __syncthreads();
  }
}

__global__ void colprefix(int* __restrict__ bh, int* __restrict__ cnt, int V){
  int r = blockIdx.x*256 + threadIdx.x;
  if (r >= V) return;
  int run = 0;
  for (int b = 0; b < NB; b++){
    long idx = (long)b*V + r;
    int t = bh[idx];
    bh[idx] = run;
    run += t;
  }
  cnt[r] = run;
}

__global__ void scan_k(const int* __restrict__ cnt, int* __restrict__ rp, int V){
  __shared__ int sh[1024];
  __shared__ int carry;
  if (threadIdx.x == 0) carry = 0;
  __syncthreads();
  for (int base = 0; base < V; base += 1024){
    int i = base + (int)threadIdx.x;
    int v = (i < V) ? cnt[i] : 0;
    sh[threadIdx.x] = v;
    __syncthreads();
    for (int off = 1; off < 1024; off <<= 1){
      int t = (threadIdx.x >= (unsigned)off) ? sh[threadIdx.x - off] : 0;
      __syncthreads();
      sh[threadIdx.x] += t;
      __syncthreads();
    }
    if (i < V) rp[i] = sh[threadIdx.x] - v + carry;
    __syncthreads();
    if (threadIdx.x == 0) carry += sh[1023];
    __syncthreads();
  }
  if (threadIdx.x == 0) rp[V] = carry;
}

__global__ void scatter2(const int* __restrict__ rows, const int* __restrict__ cols,
                         const float* __restrict__ vals,
                         const int* __restrict__ bh, const int* __restrict__ rp,
                         int* __restrict__ cs, float* __restrict__ vs, int E, int V){
  __shared__ int lh[TILE];
  int b = blockIdx.x;
  int per = (E + NB - 1) / NB;
  int e0 = b*per, e1 = (e0 + per < E) ? e0 + per : E;
  for (int t0 = 0; t0 < V; t0 += TILE){
    int tl = (V - t0 < TILE) ? (V - t0) : TILE;
    for (int i = threadIdx.x; i < tl; i += 256) lh[i] = 0;
    __syncthreads();
    for (int e = e0 + (int)threadIdx.x; e < e1; e += 256){
      int r = rows[e] - t0;
      if (r >= 0 && r < tl){
        int rank = atomicAdd(&lh[r], 1);
        int gr = t0 + r;
        int pos = rp[gr] + bh[(long)b*V + gr] + rank;
        if (pos >= 0 && pos < E){
          cs[pos] = cols[e];
          vs[pos] = vals[e];
        }
      }
    }
    __syncthreads();
  }
}

// ---------------- compute kernels ----------------

// xout[r*F+f] = alpha * sum_j vs[j]*xin[cs[j]*F+f]  (+ beta*xprev[r*F+f])
__global__ void spmv_gather(const int* __restrict__ rp, const int* __restrict__ cs,
                            const float* __restrict__ vs,
                            const float* __restrict__ xin, const float* __restrict__ xprev,
                            float* __restrict__ xout, int V, int F, float alpha, float beta){
  long t = (long)blockIdx.x*256 + threadIdx.x;
  if (t >= (long)V*F) return;
  int r = (int)(t / F), f = (int)(t % F);
  int j0 = rp[r], j1 = rp[r+1];
  float acc = 0.f;
  for (int j = j0; j < j1; j++){
    int c = cs[j];
    if (c >= 0 && c < V) acc = fmaf(vs[j], xin[(long)c*F + f], acc);
  }
  float v = alpha * acc;
  if (xprev) v += beta * xprev[t];
  xout[t] = v;
}

// out[row, o] (acc? += : =) sum_i x[row, i] * w[i, o]
__global__ void matmul_k(const float* __restrict__ x, const float* __restrict__ w,
                         float* __restrict__ out, long M, int Ci, int Co, int acc){
  long idx = (long)blockIdx.x*256 + threadIdx.x;
  if (idx >= M*Co) return;
  int  o   = (int)(idx % Co);
  long row = idx / Co;
  const float* xr = x + row*Ci;
  float a = acc ? out[idx] : 0.f;
  for (int i = 0; i < Ci; i++) a = fmaf(xr[i], w[i*Co + o], a);
  out[idx] = a;
}

__global__ void bias_elu(float* __restrict__ y, const float* __restrict__ bias, long n, int C){
  long t = (long)blockIdx.x*256 + threadIdx.x;
  if (t < n){
    int c = (int)(t % C);
    y[t] = elu_f(y[t] + bias[c]);
  }
}

// out2 [V,B,C] pre-bias -> skip (d_out, [B,V,C] fp32), pooled -> nx [V/4,B,C] fp32,
// optional pooled -> pool_out (d_out, [B,V/4,C] fp32)
__global__ void epilogue_k(const float* __restrict__ out2, const float* __restrict__ bias,
                           float* __restrict__ skip_out, float* __restrict__ nx,
                           float* __restrict__ pool_out, int V, int C){
  long t = (long)blockIdx.x*256 + threadIdx.x;
  long total = (long)(V/4)*BB*C;
  if (t >= total) return;
  int  c  = (int)(t % C);
  long bv = t / C;
  int  b  = (int)(bv % BB);
  int  v2 = (int)(bv / BB);
  float bia = bias[c];
  float s = 0.f;
  for (int j = 0; j < 4; j++){
    long v = (long)4*v2 + j;
    float val = elu_f(out2[(v*BB + b)*C + c] + bia);
    skip_out[((long)b*V + v)*C + c] = val;
    s += val;
  }
  s *= 0.25f;
  nx[((long)v2*BB + b)*C + c] = s;
  if (pool_out) pool_out[((long)b*(V/4) + v2)*C + c] = s;
}

// fires only if the host saw an unexpected out_size (diagnostic)
__global__ void guard_k(float* __restrict__ out0, int code){
  if (threadIdx.x == 0) out0[0] = 1.0e6f + (float)code;
}

// ---------------- host driver ----------------

static void run_cheb(float* x0, float* p1, float* p2, float* outb, const float* w,
                     int V, int Ci, int Co, const int* rp, const int* cs, const float* vs,
                     hipStream_t stream){
  long M = (long)V*BB;
  long tot = M*Co;
  int F = BB*Ci;
  long n = (long)V*F;

  matmul_k   <<<GRD(tot), 256, 0, stream>>>(x0, w, outb, M, Ci, Co, 0);
  spmv_gather<<<GRD(n),   256, 0, stream>>>(rp, cs, vs, x0, nullptr, p1, V, F, 1.f, 0.f);
  matmul_k   <<<GRD(tot), 256, 0, stream>>>(p1, w + (size_t)Ci*Co, outb, M, Ci, Co, 1);

  float* xa = x0; float* xb = p1; float* xc = p2;
  for (int k = 2; k < KCH; k++){
    spmv_gather<<<GRD(n),   256, 0, stream>>>(rp, cs, vs, xb, xa, xc, V, F, 2.f, -1.f);
    matmul_k   <<<GRD(tot), 256, 0, stream>>>(xc, w + (size_t)k*Ci*Co, outb, M, Ci, Co, 1);
    float* t = xa; xa = xb; xb = xc; xc = t;
  }
}

extern "C" void kernel_launch(void* const* d_in, const int* in_sizes, int n_in,
                              void* d_out, int out_size, void* d_ws, size_t ws_size,
                              hipStream_t stream){
  const float* x_in  = (const float*)d_in[0];
  const float* w1[3] = {(const float*)d_in[1], (const float*)d_in[8],  (const float*)d_in[15]};
  const float* b1[3] = {(const float*)d_in[2], (const float*)d_in[9],  (const float*)d_in[16]};
  const float* w2[3] = {(const float*)d_in[3], (const float*)d_in[10], (const float*)d_in[17]};
  const float* b2[3] = {(const float*)d_in[4], (const float*)d_in[11], (const float*)d_in[18]};
  const int*  rows[3]= {(const int*)d_in[5],   (const int*)d_in[12],   (const int*)d_in[19]};
  const int*  cols[3]= {(const int*)d_in[6],   (const int*)d_in[13],   (const int*)d_in[20]};
  const float* vals[3]={(const float*)d_in[7], (const float*)d_in[14], (const float*)d_in[21]};
  float* out = (float*)d_out;   // fp32 output buffer (reference outputs are fp32)

  const int V[3] = {49152, 12288, 3072};
  const int E[3] = {393216, 98304, 24576};
  const int Ci1[3] = {1, 32, 64};
  const int Co1[3] = {32, 64, 128};

  // ---- workspace layout (fp32 units) ----
  float* wsf = (float*)d_ws;
  size_t off = 0;
  const size_t BUFSZ = (size_t)49152 * BB * 32;   // 12,582,912 floats
  float* BUF0 = wsf + off; off += BUFSZ;
  float* BUF1 = wsf + off; off += BUFSZ;
  float* BUF2 = wsf + off; off += BUFSZ;
  float* BUF3 = wsf + off; off += BUFSZ;
  float* NX   = wsf + off; off += (size_t)12288 * BB * 32;
  int* rp[3]; int* cs[3]; float* vsf[3];
  for (int i = 0; i < 3; i++){
    rp[i]  = (int*)(wsf + off); off += V[i] + 1;
    cs[i]  = (int*)(wsf + off); off += E[i];
    vsf[i] =        wsf + off;  off += E[i];
  }
  int* bh  = (int*)(wsf + off); off += (size_t)NB * 49152;
  int* cnt = (int*)(wsf + off); off += 49152;
  if (ws_size < off * sizeof(float)) return;

  // ---- CSR build per level (LDS atomics only) ----
  for (int i = 0; i < 3; i++){
    hist2d   <<<NB, 256, 0, stream>>>(rows[i], bh, E[i], V[i]);
    colprefix<<<GRD(V[i]), 256, 0, stream>>>(bh, cnt, V[i]);
    scan_k   <<<1, 1024, 0, stream>>>(cnt, rp[i], V[i]);
    scatter2 <<<NB, 256, 0, stream>>>(rows[i], cols[i], vals[i],
                                      bh, rp[i], cs[i], vsf[i], E[i], V[i]);
  }

  // ---- level 0 input: [B,V] -> [V,B,1] ----
  transpose_in<<<GRD(BB*V[0]), 256, 0, stream>>>(x_in, NX, V[0]);

  const long OFF_OUT[4] = {0, 12582912, 18874368, 22020096};

  for (int lvl = 0; lvl < 3; lvl++){
    int Vv = V[lvl];
    int Cm = Co1[lvl];
    // conv1: NX -> BUF0
    run_cheb(NX, BUF1, BUF2, BUF0, w1[lvl], Vv, Ci1[lvl], Cm,
             rp[lvl], cs[lvl], vsf[lvl], stream);
    long n1 = (long)Vv * BB * Cm;
    bias_elu<<<GRD(n1), 256, 0, stream>>>(BUF0, b1[lvl], n1, Cm);
    // conv2: BUF0 -> BUF3
    run_cheb(BUF0, BUF1, BUF2, BUF3, w2[lvl], Vv, Cm, Cm,
             rp[lvl], cs[lvl], vsf[lvl], stream);
    // epilogue: bias+elu -> d_out skip, pooled -> NX (and final x for lvl 2)
    long n2 = (long)(Vv/4) * BB * Cm;
    float* pool_out = (lvl == 2) ? (out + OFF_OUT[3]) : (float*)nullptr;
    epilogue_k<<<GRD(n2), 256, 0, stream>>>(BUF3, b2[lvl],
                                            out + OFF_OUT[lvl], NX, pool_out,
                                            Vv, Cm);
  }

  if (out_size != 22806528)
    guard_k<<<1, 64, 0, stream>>>(out, out_size % 4096);
}

// Round 8
// 3428.823 us; speedup vs baseline: 2.7764x; 2.7764x over previous
//
#include <hip/hip_runtime.h>
#include <math.h>

#define BB 8      // batch
#define KCH 10    // Chebyshev order
#define NB 64     // blocks for hist/scatter
#define TILE 8192 // LDS histogram tile (32 KB)
#define ROWS 64   // GEMM rows per block
#define GRD(n) ((int)(((n) + 255) / 256))

__device__ __forceinline__ float elu_f(float x){ return x > 0.f ? x : expf(x) - 1.f; }

// x input is [B, V] fp32 -> x0 [V, B] fp32
__global__ void transpose_in(const float* __restrict__ x, float* __restrict__ x0, int V){
  int i = blockIdx.x*256 + threadIdx.x;
  if (i < BB*V){
    int b = i / V, v = i - b*V;
    x0[(long)v*BB + b] = x[i];
  }
}

// ---------------- CSR build (LDS atomics only; proven exact) ----------------

__global__ void hist2d(const int* __restrict__ rows, int* __restrict__ bh, int E, int V){
  __shared__ int lh[TILE];
  int b = blockIdx.x;
  int per = (E + NB - 1) / NB;
  int e0 = b*per, e1 = (e0 + per < E) ? e0 + per : E;
  for (int t0 = 0; t0 < V; t0 += TILE){
    int tl = (V - t0 < TILE) ? (V - t0) : TILE;
    for (int i = threadIdx.x; i < tl; i += 256) lh[i] = 0;
    __syncthreads();
    for (int e = e0 + (int)threadIdx.x; e < e1; e += 256){
      int r = rows[e] - t0;
      if (r >= 0 && r < tl) atomicAdd(&lh[r], 1);
    }
    __syncthreads();
    for (int i = threadIdx.x; i < tl; i += 256) bh[(long)b*V + t0 + i] = lh[i];
    __syncthreads();
  }
}

__global__ void colprefix(int* __restrict__ bh, int* __restrict__ cnt, int V){
  int r = blockIdx.x*256 + threadIdx.x;
  if (r >= V) return;
  int run = 0;
  for (int b = 0; b < NB; b++){
    long idx = (long)b*V + r;
    int t = bh[idx];
    bh[idx] = run;
    run += t;
  }
  cnt[r] = run;
}

__global__ void scan_k(const int* __restrict__ cnt, int* __restrict__ rp, int V){
  __shared__ int sh[1024];
  __shared__ int carry;
  if (threadIdx.x == 0) carry = 0;
  __syncthreads();
  for (int base = 0; base < V; base += 1024){
    int i = base + (int)threadIdx.x;
    int v = (i < V) ? cnt[i] : 0;
    sh[threadIdx.x] = v;
    __syncthreads();
    for (int off = 1; off < 1024; off <<= 1){
      int t = (threadIdx.x >= (unsigned)off) ? sh[threadIdx.x - off] : 0;
      __syncthreads();
      sh[threadIdx.x] += t;
      __syncthreads();
    }
    if (i < V) rp[i] = sh[threadIdx.x] - v + carry;
    __syncthreads();
    if (threadIdx.x == 0) carry += sh[1023];
    __syncthreads();
  }
  if (threadIdx.x == 0) rp[V] = carry;
}

__global__ void scatter2(const int* __restrict__ rows, const int* __restrict__ cols,
                         const float* __restrict__ vals,
                         const int* __restrict__ bh, const int* __restrict__ rp,
                         int* __restrict__ cs, float* __restrict__ vs, int E, int V){
  __shared__ int lh[TILE];
  int b = blockIdx.x;
  int per = (E + NB - 1) / NB;
  int e0 = b*per, e1 = (e0 + per < E) ? e0 + per : E;
  for (int t0 = 0; t0 < V; t0 += TILE){
    int tl = (V - t0 < TILE) ? (V - t0) : TILE;
    for (int i = threadIdx.x; i < tl; i += 256) lh[i] = 0;
    __syncthreads();
    for (int e = e0 + (int)threadIdx.x; e < e1; e += 256){
      int r = rows[e] - t0;
      if (r >= 0 && r < tl){
        int rank = atomicAdd(&lh[r], 1);
        int gr = t0 + r;
        int pos = rp[gr] + bh[(long)b*V + gr] + rank;
        if (pos >= 0 && pos < E){
          cs[pos] = cols[e];
          vs[pos] = vals[e];
        }
      }
    }
    __syncthreads();
  }
}

// ---------------- SpMV: float4 row-gather ----------------
// xout[r][f4] = alpha * sum_j vs[j]*xin[cs[j]][f4] (+ beta*xprev[r][f4]), float4 lanes.
// F4 = F/4 = 1<<lf4 (power of two).
__global__ __launch_bounds__(256) void spmv_gather4(
    const int* __restrict__ rp, const int* __restrict__ cs, const float* __restrict__ vs,
    const float4* __restrict__ xin, const float4* __restrict__ xprev,
    float4* __restrict__ xout, int V, int lf4, float alpha, float beta){
  long t = (long)blockIdx.x*256 + threadIdx.x;
  if (t >= ((long)V << lf4)) return;
  int r  = (int)(t >> lf4);
  int f4 = (int)(t - ((long)r << lf4));
  int j0 = rp[r], j1 = rp[r+1];
  float ax = 0.f, ay = 0.f, az = 0.f, aw = 0.f;
  for (int j = j0; j < j1; j++){
    int   c = cs[j];
    float v = vs[j];
    float4 g = xin[((long)c << lf4) + f4];
    ax = fmaf(v, g.x, ax); ay = fmaf(v, g.y, ay);
    az = fmaf(v, g.z, az); aw = fmaf(v, g.w, aw);
  }
  float4 o;
  o.x = alpha*ax; o.y = alpha*ay; o.z = alpha*az; o.w = alpha*aw;
  if (xprev){
    float4 p = xprev[t];
    o.x = fmaf(beta, p.x, o.x); o.y = fmaf(beta, p.y, o.y);
    o.z = fmaf(beta, p.z, o.z); o.w = fmaf(beta, p.w, o.w);
  }
  xout[t] = o;
}

// ---------------- tiled GEMM: C[M,Co] (acc?+=:=) A[M,Ci] @ W[Ci,Co] ----------------
// W staged in LDS (Ci*Co*4 B <= 64 KB). Block = ROWS(64) rows x all Co cols.
// Thread (tc=tid&15, tr=tid>>4) computes 4 rows x TN cols (cols tc + j*16).
// Optional fused bias+ELU on the final accumulation pass.
template<int TN>
__global__ __launch_bounds__(256) void gemm_k(
    const float* __restrict__ A, const float* __restrict__ W,
    const float* __restrict__ bias, float* __restrict__ C,
    int Ci, int Co, int acc, int do_elu){
  extern __shared__ float ws[];   // Ci*Co floats
  int tid = threadIdx.x;
  int nw = Ci*Co;
  for (int i = tid; i < nw; i += 256) ws[i] = W[i];
  __syncthreads();

  const int tc = tid & 15, tr = tid >> 4;
  const long r0 = (long)blockIdx.x * ROWS + (long)tr * 4;
  const float* Ar = A + r0 * Ci;

  float accv[4][TN];
  #pragma unroll
  for (int m = 0; m < 4; m++)
    #pragma unroll
    for (int j = 0; j < TN; j++) accv[m][j] = 0.f;

  if ((Ci & 3) == 0){
    for (int i = 0; i < Ci; i += 4){
      float4 a0 = *(const float4*)(Ar + 0*Ci + i);
      float4 a1 = *(const float4*)(Ar + 1*Ci + i);
      float4 a2 = *(const float4*)(Ar + 2*Ci + i);
      float4 a3 = *(const float4*)(Ar + 3*Ci + i);
      float am[4][4] = {{a0.x,a0.y,a0.z,a0.w},{a1.x,a1.y,a1.z,a1.w},
                        {a2.x,a2.y,a2.z,a2.w},{a3.x,a3.y,a3.z,a3.w}};
      #pragma unroll
      for (int ii = 0; ii < 4; ii++){
        const float* wr = &ws[(i+ii)*Co + tc];
        #pragma unroll
        for (int j = 0; j < TN; j++){
          float wv = wr[j*16];
          #pragma unroll
          for (int m = 0; m < 4; m++)
            accv[m][j] = fmaf(am[m][ii], wv, accv[m][j]);
        }
      }
    }
  } else {
    for (int i = 0; i < Ci; i++){
      float am[4] = {Ar[0*Ci+i], Ar[1*Ci+i], Ar[2*Ci+i], Ar[3*Ci+i]};
      const float* wr = &ws[i*Co + tc];
      #pragma unroll
      for (int j = 0; j < TN; j++){
        float wv = wr[j*16];
        #pragma unroll
        for (int m = 0; m < 4; m++)
          accv[m][j] = fmaf(am[m], wv, accv[m][j]);
      }
    }
  }

  #pragma unroll
  for (int m = 0; m < 4; m++){
    float* Cr = C + (r0 + m)*Co;
    #pragma unroll
    for (int j = 0; j < TN; j++){
      int col = tc + j*16;
      float v = accv[m][j];
      if (acc) v += Cr[col];
      if (do_elu) v = elu_f(v + bias[col]);
      Cr[col] = v;
    }
  }
}

static void launch_gemm(const float* A, const float* W, const float* bias, float* C,
                        long M, int Ci, int Co, int acc, int do_elu, hipStream_t stream){
  int grid = (int)(M / ROWS);
  size_t sh = (size_t)Ci * Co * sizeof(float);
  int tn = Co / 16;
  if (tn == 2)      gemm_k<2><<<grid, 256, sh, stream>>>(A, W, bias, C, Ci, Co, acc, do_elu);
  else if (tn == 4) gemm_k<4><<<grid, 256, sh, stream>>>(A, W, bias, C, Ci, Co, acc, do_elu);
  else              gemm_k<8><<<grid, 256, sh, stream>>>(A, W, bias, C, Ci, Co, acc, do_elu);
}

// out2 [V,B,C] pre-bias -> skip (d_out, [B,V,C] fp32), pooled -> nx [V/4,B,C] fp32,
// optional pooled -> pool_out (d_out, [B,V/4,C] fp32)
__global__ void epilogue_k(const float* __restrict__ out2, const float* __restrict__ bias,
                           float* __restrict__ skip_out, float* __restrict__ nx,
                           float* __restrict__ pool_out, int V, int C){
  long t = (long)blockIdx.x*256 + threadIdx.x;
  long total = (long)(V/4)*BB*C;
  if (t >= total) return;
  int  c  = (int)(t % C);
  long bv = t / C;
  int  b  = (int)(bv % BB);
  int  v2 = (int)(bv / BB);
  float bia = bias[c];
  float s = 0.f;
  for (int j = 0; j < 4; j++){
    long v = (long)4*v2 + j;
    float val = elu_f(out2[(v*BB + b)*C + c] + bia);
    skip_out[((long)b*V + v)*C + c] = val;
    s += val;
  }
  s *= 0.25f;
  nx[((long)v2*BB + b)*C + c] = s;
  if (pool_out) pool_out[((long)b*(V/4) + v2)*C + c] = s;
}

__global__ void guard_k(float* __restrict__ out0, int code){
  if (threadIdx.x == 0) out0[0] = 1.0e6f + (float)code;
}

// ---------------- host driver ----------------

static int ilog2(int x){ int l = 0; while ((1 << l) < x) l++; return l; }

// One ChebConv: out = sum_k T_k(L) x0 @ w[k]; if bias!=null fuse bias+ELU on last pass.
static void run_cheb(float* x0, float* p1, float* p2, float* outb,
                     const float* w, const float* bias,
                     int V, int Ci, int Co, const int* rp, const int* cs, const float* vs,
                     hipStream_t stream){
  long M = (long)V*BB;
  int F4 = BB*Ci/4;
  int lf4 = ilog2(F4);
  long n4 = (long)V*F4;

  // k = 0
  launch_gemm(x0, w, bias, outb, M, Ci, Co, 0, 0, stream);
  // k = 1: x1 = L x0
  spmv_gather4<<<GRD(n4), 256, 0, stream>>>(rp, cs, vs, (const float4*)x0, nullptr,
                                            (float4*)p1, V, lf4, 1.f, 0.f);
  launch_gemm(p1, w + (size_t)Ci*Co, bias, outb, M, Ci, Co, 1,
              (bias && KCH == 2) ? 1 : 0, stream);

  float* xa = x0; float* xb = p1; float* xc = p2;
  for (int k = 2; k < KCH; k++){
    // x2 = 2 L x1 - x0
    spmv_gather4<<<GRD(n4), 256, 0, stream>>>(rp, cs, vs, (const float4*)xb,
                                              (const float4*)xa, (float4*)xc, V, lf4,
                                              2.f, -1.f);
    launch_gemm(xc, w + (size_t)k*Ci*Co, bias, outb, M, Ci, Co, 1,
                (bias && k == KCH-1) ? 1 : 0, stream);
    float* t = xa; xa = xb; xb = xc; xc = t;
  }
}

extern "C" void kernel_launch(void* const* d_in, const int* in_sizes, int n_in,
                              void* d_out, int out_size, void* d_ws, size_t ws_size,
                              hipStream_t stream){
  const float* x_in  = (const float*)d_in[0];
  const float* w1[3] = {(const float*)d_in[1], (const float*)d_in[8],  (const float*)d_in[15]};
  const float* b1[3] = {(const float*)d_in[2], (const float*)d_in[9],  (const float*)d_in[16]};
  const float* w2[3] = {(const float*)d_in[3], (const float*)d_in[10], (const float*)d_in[17]};
  const float* b2[3] = {(const float*)d_in[4], (const float*)d_in[11], (const float*)d_in[18]};
  const int*  rows[3]= {(const int*)d_in[5],   (const int*)d_in[12],   (const int*)d_in[19]};
  const int*  cols[3]= {(const int*)d_in[6],   (const int*)d_in[13],   (const int*)d_in[20]};
  const float* vals[3]={(const float*)d_in[7], (const float*)d_in[14], (const float*)d_in[21]};
  float* out = (float*)d_out;

  const int V[3] = {49152, 12288, 3072};
  const int E[3] = {393216, 98304, 24576};
  const int Ci1[3] = {1, 32, 64};
  const int Co1[3] = {32, 64, 128};

  // ---- workspace layout (fp32 units) — identical footprint to the proven R7 layout ----
  float* wsf = (float*)d_ws;
  size_t off = 0;
  const size_t BUFSZ = (size_t)49152 * BB * 32;   // 12,582,912 floats
  float* BUF0 = wsf + off; off += BUFSZ;
  float* BUF1 = wsf + off; off += BUFSZ;
  float* BUF2 = wsf + off; off += BUFSZ;
  float* BUF3 = wsf + off; off += BUFSZ;
  float* NX   = wsf + off; off += (size_t)12288 * BB * 32;
  int* rp[3]; int* cs[3]; float* vsf[3];
  for (int i = 0; i < 3; i++){
    rp[i]  = (int*)(wsf + off); off += V[i] + 1;
    cs[i]  = (int*)(wsf + off); off += E[i];
    vsf[i] =        wsf + off;  off += E[i];
  }
  int* bh  = (int*)(wsf + off); off += (size_t)NB * 49152;
  int* cnt = (int*)(wsf + off); off += 49152;
  if (ws_size < off * sizeof(float)) return;

  // ---- CSR build per level ----
  for (int i = 0; i < 3; i++){
    hist2d   <<<NB, 256, 0, stream>>>(rows[i], bh, E[i], V[i]);
    colprefix<<<GRD(V[i]), 256, 0, stream>>>(bh, cnt, V[i]);
    scan_k   <<<1, 1024, 0, stream>>>(cnt, rp[i], V[i]);
    scatter2 <<<NB, 256, 0, stream>>>(rows[i], cols[i], vals[i],
                                      bh, rp[i], cs[i], vsf[i], E[i], V[i]);
  }

  // ---- level 0 input: [B,V] -> [V,B,1] ----
  transpose_in<<<GRD(BB*V[0]), 256, 0, stream>>>(x_in, NX, V[0]);

  const long OFF_OUT[4] = {0, 12582912, 18874368, 22020096};

  for (int lvl = 0; lvl < 3; lvl++){
    int Vv = V[lvl];
    int Cm = Co1[lvl];
    // conv1: NX -> BUF0 (bias+ELU fused into final GEMM pass)
    run_cheb(NX, BUF1, BUF2, BUF0, w1[lvl], b1[lvl], Vv, Ci1[lvl], Cm,
             rp[lvl], cs[lvl], vsf[lvl], stream);
    // conv2: BUF0 -> BUF3 (raw; epilogue applies bias+ELU+pool)
    run_cheb(BUF0, BUF1, BUF2, BUF3, w2[lvl], nullptr, Vv, Cm, Cm,
             rp[lvl], cs[lvl], vsf[lvl], stream);
    long n2 = (long)(Vv/4) * BB * Cm;
    float* pool_out = (lvl == 2) ? (out + OFF_OUT[3]) : (float*)nullptr;
    epilogue_k<<<GRD(n2), 256, 0, stream>>>(BUF3, b2[lvl],
                                            out + OFF_OUT[lvl], NX, pool_out,
                                            Vv, Cm);
  }

  if (out_size != 22806528)
    guard_k<<<1, 64, 0, stream>>>(out, out_size % 4096);
}